// Round 6
// baseline (118.973 us; speedup 1.0000x reference)
//
#include <hip/hip_runtime.h>

// feature_seq (B=2, C=64, N=512) fp32. Window lengths [256, 1024, 512, 512].
// Output i is (B, N, C, L_i), concatenated flat in d_out.
// out[b][n][c][l] = (0 <= n - L/2 + l < N) ? in[b][c][n - L/2 + l] : 0
//
// Key structural fact: with t = ((b*N+n)*C+c)*L4 + l4 and 64-lane waves,
// (b,c,n) is IDENTICAL across a wave (L4 >= 64 and all strides are
// 64-multiples) — only l4 varies per lane. So each wave gathers from ONE
// input row. Build a per-row buffer descriptor (num_records = N*4 bytes)
// and gather with a single buffer_load_dwordx4: hardware bounds checking
// zero-fills fully-OOB lanes (negative idx -> huge unsigned voffset -> OOB
// -> 0). Partial-straddle float4s only exist when n%4 != 0; detected with
// a wave-uniform __any() and handled on a scalar path.

constexpr int B = 2;
constexpr int C = 64;   // log2 = 6
constexpr int N = 512;  // log2 = 9

constexpr int SZ256  = B * N * C * 256;   // 16,777,216 floats
constexpr int SZ1024 = B * N * C * 1024;  // 67,108,864
constexpr int SZ512  = B * N * C * 512;   // 33,554,432

constexpr int BLK256  = SZ256  / 4 / 1024;  // 4096 blocks
constexpr int BLK1024 = SZ1024 / 4 / 1024;  // 16384
constexpr int BLK512  = SZ512  / 4 / 1024;  // 8192
constexpr int NBLK = BLK256 + BLK1024 + 2 * BLK512;  // 36864

typedef float f32x4 __attribute__((ext_vector_type(4)));

template <int L>
__device__ __forceinline__ void do_seg(const float* __restrict__ in,
                                       float* __restrict__ out,
                                       int blk, int tid) {
    constexpr int HALF = L / 2;
    constexpr int L4 = L / 4;
    constexpr int L4_BITS = (L == 256) ? 6 : (L == 512) ? 7 : 8;
    constexpr int KS = 256 >> L4_BITS;   // rest step per k

    f32x4* __restrict__ out4 = reinterpret_cast<f32x4*>(out);

    const int l4    = tid & (L4 - 1);         // k-invariant
    const int lb    = l4 << 2;                // window-local element offset
    const int restT = tid >> L4_BITS;
    const int R0    = (blk * 1024) >> L4_BITS;

#pragma unroll
    for (int k = 0; k < 4; ++k) {
        int t    = blk * 1024 + k * 256 + tid;
        int rest = R0 + k * KS + restT;       // wave-uniform

        int c  = rest & (C - 1);
        int bb = rest >> 15;                  // rest / (N*C)
        int n  = (rest >> 6) & (N - 1);

        // wave-uniform row offset -> SGPR, so make_buffer_rsrc is uniform
        int roff = __builtin_amdgcn_readfirstlane((((bb << 6) | c) << 9));
        const float* __restrict__ row = in + roff;

        int idx = n - HALF + lb;              // per-lane window source index

        f32x4 v;
        // partial float4 straddles a boundary (only possible when n%4 != 0)
        bool partial = ((idx > -4) && (idx < 0)) || ((idx > N - 4) && (idx < N));
        if (__any(partial)) {
            // boundary wave: scalar path (rare)
            v.x = ((unsigned)(idx)     < (unsigned)N) ? row[idx]     : 0.0f;
            v.y = ((unsigned)(idx + 1) < (unsigned)N) ? row[idx + 1] : 0.0f;
            v.z = ((unsigned)(idx + 2) < (unsigned)N) ? row[idx + 2] : 0.0f;
            v.w = ((unsigned)(idx + 3) < (unsigned)N) ? row[idx + 3] : 0.0f;
        } else {
            // hot path: one buffer gather; HW bounds check zero-fills OOB lanes
            __amdgpu_buffer_rsrc_t srd = __builtin_amdgcn_make_buffer_rsrc(
                (void*)row, /*stride=*/(short)0,
                /*num_records=*/N * 4, /*flags=*/0x00020000);
            auto lv = __builtin_amdgcn_raw_buffer_load_b128(
                srd, (unsigned)(idx << 2), 0, 0);
            v = __builtin_bit_cast(f32x4, lv);
        }

        __builtin_nontemporal_store(v, out4 + t);
    }
}

__global__ __launch_bounds__(256)
void msw_fused_kernel(const float* __restrict__ in, float* __restrict__ out) {
    const int blk = blockIdx.x;
    const int tid = threadIdx.x;

    if (blk < BLK256) {
        do_seg<256>(in, out, blk, tid);
    } else if (blk < BLK256 + BLK1024) {
        do_seg<1024>(in, out + SZ256, blk - BLK256, tid);
    } else if (blk < BLK256 + BLK1024 + BLK512) {
        do_seg<512>(in, out + SZ256 + SZ1024, blk - (BLK256 + BLK1024), tid);
    } else {
        do_seg<512>(in, out + SZ256 + SZ1024 + SZ512,
                    blk - (BLK256 + BLK1024 + BLK512), tid);
    }
}

extern "C" void kernel_launch(void* const* d_in, const int* in_sizes, int n_in,
                              void* d_out, int out_size, void* d_ws, size_t ws_size,
                              hipStream_t stream) {
    const float* in = (const float*)d_in[0];
    float* out = (float*)d_out;

    msw_fused_kernel<<<NBLK, 256, 0, stream>>>(in, out);
}